// Round 9
// baseline (64.976 us; speedup 1.0000x reference)
//
#include <hip/hip_runtime.h>
#include <hip/hip_bf16.h>

#define NSEG 512
#define EPSF 1e-6f
#define MAIN_GRID 1280   // 5 blocks/CU x 256 CU
#define MAIN_BLOCK 256
#define WAVES_PER_BLOCK 4

// d_ws layout:
//   [0, 16KB)            : gacc f64[2048] ([0..511]=count, [512..1023]=sum_x,
//                          [1024..1535]=sum_log, [1536..2047]=sum_log2)
//   [16KB, 16KB+10.5MB)  : per-block f32 partials, entry layout e = s*4+f

__global__ __launch_bounds__(1024) void zero_ws_kernel(double* __restrict__ g) {
    int i = blockIdx.x * blockDim.x + threadIdx.x;
    if (i < 4 * NSEG) g[i] = 0.0;
}

__global__ __launch_bounds__(MAIN_BLOCK) void seg_stats_kernel(const float4* __restrict__ x4,
                                                               const int4* __restrict__ i4,
                                                               float* __restrict__ parts,
                                                               double* __restrict__ gacc,
                                                               int n4, int use_parts) {
    // Per-wave private histogram, NO tag array. Election by atomic exchange
    // on the count field: old = atomicExch(&h[s].x, -1.0f). The exchange
    // chain hands the ORIGINAL value (the real count, always >= 0) to exactly
    // one item per segment per round -> that item is the winner AND already
    // holds the count half of its RMW. Winners commit {old+1, y+v, z+lx,
    // w+lx^2}; losers (got -1) retry. Per-wave in-order DS ensures each
    // round's commits are visible to the next round's exchanges.
    __shared__ float4 hist4[WAVES_PER_BLOCK][NSEG];  // 32 KB exactly

    const int wave = threadIdx.x >> 6;
    float4* h = hist4[wave];

    for (int i = threadIdx.x; i < WAVES_PER_BLOCK * NSEG; i += MAIN_BLOCK)
        ((float4*)hist4)[i] = make_float4(0.f, 0.f, 0.f, 0.f);
    __syncthreads();

    const int stride = gridDim.x * blockDim.x;
    int i = blockIdx.x * blockDim.x + threadIdx.x;
    if (i < n4) {
        float4 xv = x4[i];
        int4 iv = i4[i];
        while (true) {
            // prefetch next sweep (issued before any clobber)
            int inext = i + stride;
            bool more = inext < n4;
            float4 xv_n;
            int4 iv_n;
            if (more) {
                xv_n = x4[inext];
                iv_n = i4[inext];
            }

            float v[4] = {xv.x, xv.y, xv.z, xv.w};
            int s[4] = {iv.x, iv.y, iv.z, iv.w};
            float lx[4];
#pragma unroll
            for (int c = 0; c < 4; ++c) lx[c] = __logf(fabsf(v[c]) + EPSF);

            // ---- round 1: xchg-election + speculative hist read ----
            float old[4];
#pragma unroll
            for (int c = 0; c < 4; ++c) old[c] = atomicExch(&h[s[c]].x, -1.0f);
            float4 hv[4];
#pragma unroll
            for (int c = 0; c < 4; ++c) hv[c] = h[s[c]];
            __asm__ volatile("" ::: "memory");
            unsigned pend = 0;
#pragma unroll
            for (int c = 0; c < 4; ++c) {
                if (old[c] >= 0.0f) {
                    h[s[c]] = make_float4(old[c] + 1.0f, hv[c].y + v[c],
                                          hv[c].z + lx[c], hv[c].w + lx[c] * lx[c]);
                } else {
                    pend |= (1u << c);
                }
            }

            // ---- sparse rounds: one compacted slot per thread ----
            while (__ballot(pend != 0)) {
                bool act = pend != 0;
                int k = 0;
                int s0 = 0;
                float v0 = 0.f, l0 = 0.f;
                if (act) {
                    k = __ffs(pend) - 1;
                    s0 = (k == 0) ? s[0] : (k == 1) ? s[1] : (k == 2) ? s[2] : s[3];
                    v0 = (k == 0) ? v[0] : (k == 1) ? v[1] : (k == 2) ? v[2] : v[3];
                    l0 = (k == 0) ? lx[0] : (k == 1) ? lx[1] : (k == 2) ? lx[2] : lx[3];
                }
                float old0 = -1.0f;
                if (act) old0 = atomicExch(&h[s0].x, -1.0f);
                float4 hv0 = make_float4(0.f, 0.f, 0.f, 0.f);
                if (act) hv0 = h[s0];
                __asm__ volatile("" ::: "memory");
                if (act && old0 >= 0.0f) {
                    h[s0] = make_float4(old0 + 1.0f, hv0.y + v0, hv0.z + l0,
                                        hv0.w + l0 * l0);
                    pend &= ~(1u << k);
                }
            }

            if (!__ballot(more)) break;
            i = inext;
            xv = xv_n;
            iv = iv_n;
        }
    }
    __syncthreads();

    // Combine the 4 wave copies; flush per block (float4 = entry layout s*4+f).
    for (int sg = threadIdx.x; sg < NSEG; sg += MAIN_BLOCK) {
        float4 a = hist4[0][sg];
        float4 b = hist4[1][sg];
        float4 cc = hist4[2][sg];
        float4 d = hist4[3][sg];
        float4 t = make_float4(a.x + b.x + cc.x + d.x, a.y + b.y + cc.y + d.y,
                               a.z + b.z + cc.z + d.z, a.w + b.w + cc.w + d.w);
        if (use_parts) {
            *(float4*)(parts + (size_t)blockIdx.x * (NSEG * 4) + (sg << 2)) = t;
        } else {
            if (t.x != 0.0f) unsafeAtomicAdd(&gacc[0 * NSEG + sg], (double)t.x);
            if (t.y != 0.0f) unsafeAtomicAdd(&gacc[1 * NSEG + sg], (double)t.y);
            if (t.z != 0.0f) unsafeAtomicAdd(&gacc[2 * NSEG + sg], (double)t.z);
            if (t.w != 0.0f) unsafeAtomicAdd(&gacc[3 * NSEG + sg], (double)t.w);
        }
    }
}

#define RP_CHUNKS 16  // 1280 partial blocks / 80 per chunk
__global__ __launch_bounds__(256) void reduce_partials_kernel(const float* __restrict__ parts,
                                                              double* __restrict__ gacc) {
    int eg = blockIdx.x & 7;
    int bc = blockIdx.x >> 3;
    int e = eg * 256 + threadIdx.x;  // 0..2047, entry layout s*4+f
    int b0 = bc * (MAIN_GRID / RP_CHUNKS);
    double acc = 0.0;
    for (int b = 0; b < MAIN_GRID / RP_CHUNKS; ++b)
        acc += (double)parts[(size_t)(b0 + b) * (NSEG * 4) + e];
    unsafeAtomicAdd(&gacc[(e & 3) * NSEG + (e >> 2)], acc);
}

__global__ __launch_bounds__(512) void finalize_kernel(const double* __restrict__ gacc,
                                                       const float* __restrict__ tmean,
                                                       const float* __restrict__ tstd,
                                                       float* __restrict__ out) {
    int s = threadIdx.x;  // 512 threads, one per segment
    double cnt = gacc[s];
    double c = cnt > 1.0 ? cnt : 1.0;
    double mean_w = gacc[NSEG + s] / c;
    double mean_log = gacc[2 * NSEG + s] / c;
    double var = gacc[3 * NSEG + s] / c - mean_log * mean_log;
    if (var < 0.0) var = 0.0;
    double std_w = sqrt(var + 1e-6);
    double dm = mean_w - (double)tmean[s];
    double dsd = std_w - (double)tstd[s];
    double term = 0.5 * dm * dm + 0.5 * dsd * dsd;

#pragma unroll
    for (int off = 32; off > 0; off >>= 1) term += __shfl_down(term, off, 64);

    __shared__ double part[8];
    int wid = threadIdx.x >> 6;
    if ((threadIdx.x & 63) == 0) part[wid] = term;
    __syncthreads();
    if (threadIdx.x == 0) {
        double t = 0.0;
#pragma unroll
        for (int i = 0; i < 8; ++i) t += part[i];
        out[0] = (float)((t / (double)NSEG) * 0.01);
    }
}

extern "C" void kernel_launch(void* const* d_in, const int* in_sizes, int n_in,
                              void* d_out, int out_size, void* d_ws, size_t ws_size,
                              hipStream_t stream) {
    const float* x = (const float*)d_in[0];
    const int* idx = (const int*)d_in[1];
    const float* tmean = (const float*)d_in[2];
    const float* tstd = (const float*)d_in[3];
    float* out = (float*)d_out;

    double* gacc = (double*)d_ws;
    float* parts = (float*)((char*)d_ws + 4 * NSEG * sizeof(double));
    size_t need = 4 * NSEG * sizeof(double) + (size_t)MAIN_GRID * NSEG * 4 * sizeof(float);
    int use_parts = (ws_size >= need) ? 1 : 0;

    int n = in_sizes[0];
    int n4 = n / 4;  // N_EDGES = 16777216, divisible by 4

    zero_ws_kernel<<<2, 1024, 0, stream>>>(gacc);
    seg_stats_kernel<<<MAIN_GRID, MAIN_BLOCK, 0, stream>>>((const float4*)x, (const int4*)idx,
                                                           parts, gacc, n4, use_parts);
    if (use_parts)
        reduce_partials_kernel<<<8 * RP_CHUNKS, 256, 0, stream>>>(parts, gacc);
    finalize_kernel<<<1, 512, 0, stream>>>(gacc, tmean, tstd, out);
}

// Round 10
// 55.291 us; speedup vs baseline: 1.1752x; 1.1752x over previous
//
#include <hip/hip_runtime.h>
#include <hip/hip_bf16.h>

#define NSEG 512
#define EPSF 1e-6f
#define MAIN_GRID 1024
#define MAIN_BLOCK 256
#define WAVES_PER_BLOCK 4

// d_ws layout:
//   [0, 16KB)          : gacc f64[2048] ([0..511]=count, [512..1023]=sum_x,
//                        [1024..1535]=sum_log, [1536..2047]=sum_log2)
//   [16KB, 16KB+8MB)   : per-block f32 partials, entry layout e = s*4+f

__global__ __launch_bounds__(1024) void zero_ws_kernel(double* __restrict__ g) {
    int i = blockIdx.x * blockDim.x + threadIdx.x;
    if (i < 4 * NSEG) g[i] = 0.0;
}

__global__ __launch_bounds__(MAIN_BLOCK) void seg_stats_kernel(const float4* __restrict__ x4,
                                                               const int4* __restrict__ i4,
                                                               float* __restrict__ parts,
                                                               double* __restrict__ gacc,
                                                               int n4, int use_parts) {
    // Per-wave private histogram with the election tag PACKED INTO the entry:
    //   word0 = (tag:u16 << 16) | count:u16 ; words1-3 = sum_x, sum_log, sum_log2
    // Election: pending items ds_write_b16 their code into the tag half, then
    // ONE speculative ds_read_b128 returns tag+count+sums together. Winner
    // (tag == own code) commits b128 {count+1 (tag=0), sums+contrib}. A tag
    // reader always wrote its own code earlier in the same round (per-wave
    // program order), so stale tags / the commit's tag=0 are never observed.
    // Codes are +1-offset so 0 is never a valid code.
    __shared__ float4 hist4[WAVES_PER_BLOCK][NSEG];  // 32 KB exactly, no tag array

    const int wave = threadIdx.x >> 6;
    const int lane = threadIdx.x & 63;
    float4* h = hist4[wave];
    unsigned short* tagp = (unsigned short*)h;  // entry s -> shorts [s*8..s*8+7]; tag = s*8+1

    for (int i = threadIdx.x; i < WAVES_PER_BLOCK * NSEG; i += MAIN_BLOCK)
        ((float4*)hist4)[i] = make_float4(0.f, 0.f, 0.f, 0.f);
    __syncthreads();

    const int stride = gridDim.x * blockDim.x;
    int i = blockIdx.x * blockDim.x + threadIdx.x;
    if (i < n4) {
        float4 xv = x4[i];
        int4 iv = i4[i];
        while (true) {
            // prefetch next sweep (issued before any clobber)
            int inext = i + stride;
            bool more = inext < n4;
            float4 xv_n;
            int4 iv_n;
            if (more) {
                xv_n = x4[inext];
                iv_n = i4[inext];
            }

            float v[4] = {xv.x, xv.y, xv.z, xv.w};
            int s[4] = {iv.x, iv.y, iv.z, iv.w};
            float lx[4];
#pragma unroll
            for (int c = 0; c < 4; ++c) lx[c] = __logf(fabsf(v[c]) + EPSF);

            // ---- round 1: tag write (b16) + speculative b128 read ----
#pragma unroll
            for (int c = 0; c < 4; ++c)
                tagp[(s[c] << 3) + 1] = (unsigned short)(((c << 6) | lane) + 1);
            __asm__ volatile("" ::: "memory");
            float4 hv[4];
#pragma unroll
            for (int c = 0; c < 4; ++c) hv[c] = h[s[c]];
            __asm__ volatile("" ::: "memory");
            unsigned pend = 0;
#pragma unroll
            for (int c = 0; c < 4; ++c) {
                unsigned w0 = __float_as_uint(hv[c].x);
                if ((w0 >> 16) == (unsigned)(((c << 6) | lane) + 1)) {
                    h[s[c]] = make_float4(__uint_as_float((w0 & 0xFFFFu) + 1u),
                                          hv[c].y + v[c], hv[c].z + lx[c],
                                          hv[c].w + lx[c] * lx[c]);
                } else {
                    pend |= (1u << c);
                }
            }

            // ---- sparse rounds: one compacted slot per thread ----
            while (__ballot(pend != 0)) {
                bool act = pend != 0;
                int k = 0;
                int s0 = 0;
                float v0 = 0.f, l0 = 0.f;
                if (act) {
                    k = __ffs(pend) - 1;
                    s0 = (k == 0) ? s[0] : (k == 1) ? s[1] : (k == 2) ? s[2] : s[3];
                    v0 = (k == 0) ? v[0] : (k == 1) ? v[1] : (k == 2) ? v[2] : v[3];
                    l0 = (k == 0) ? lx[0] : (k == 1) ? lx[1] : (k == 2) ? lx[2] : lx[3];
                    tagp[(s0 << 3) + 1] = (unsigned short)(lane + 1);
                }
                __asm__ volatile("" ::: "memory");
                float4 hv0 = make_float4(0.f, 0.f, 0.f, 0.f);
                if (act) hv0 = h[s0];
                __asm__ volatile("" ::: "memory");
                if (act) {
                    unsigned w0 = __float_as_uint(hv0.x);
                    if ((w0 >> 16) == (unsigned)(lane + 1)) {
                        h[s0] = make_float4(__uint_as_float((w0 & 0xFFFFu) + 1u),
                                            hv0.y + v0, hv0.z + l0, hv0.w + l0 * l0);
                        pend &= ~(1u << k);
                    }
                }
            }

            if (!__ballot(more)) break;
            i = inext;
            xv = xv_n;
            iv = iv_n;
        }
    }
    __syncthreads();

    // Combine the 4 wave copies; flush per block (float4 = entry layout s*4+f).
    for (int sg = threadIdx.x; sg < NSEG; sg += MAIN_BLOCK) {
        float4 a = hist4[0][sg];
        float4 b = hist4[1][sg];
        float4 cc = hist4[2][sg];
        float4 d = hist4[3][sg];
        unsigned cnt = (__float_as_uint(a.x) & 0xFFFFu) + (__float_as_uint(b.x) & 0xFFFFu) +
                       (__float_as_uint(cc.x) & 0xFFFFu) + (__float_as_uint(d.x) & 0xFFFFu);
        float4 t = make_float4((float)cnt, a.y + b.y + cc.y + d.y,
                               a.z + b.z + cc.z + d.z, a.w + b.w + cc.w + d.w);
        if (use_parts) {
            *(float4*)(parts + (size_t)blockIdx.x * (NSEG * 4) + (sg << 2)) = t;
        } else {
            if (t.x != 0.0f) unsafeAtomicAdd(&gacc[0 * NSEG + sg], (double)t.x);
            if (t.y != 0.0f) unsafeAtomicAdd(&gacc[1 * NSEG + sg], (double)t.y);
            if (t.z != 0.0f) unsafeAtomicAdd(&gacc[2 * NSEG + sg], (double)t.z);
            if (t.w != 0.0f) unsafeAtomicAdd(&gacc[3 * NSEG + sg], (double)t.w);
        }
    }
}

#define RP_CHUNKS 16  // 1024 partial blocks / 64 per chunk
__global__ __launch_bounds__(256) void reduce_partials_kernel(const float* __restrict__ parts,
                                                              double* __restrict__ gacc) {
    int eg = blockIdx.x & 7;
    int bc = blockIdx.x >> 3;
    int e = eg * 256 + threadIdx.x;  // 0..2047, entry layout s*4+f
    int b0 = bc * (MAIN_GRID / RP_CHUNKS);
    double acc = 0.0;
    for (int b = 0; b < MAIN_GRID / RP_CHUNKS; ++b)
        acc += (double)parts[(size_t)(b0 + b) * (NSEG * 4) + e];
    unsafeAtomicAdd(&gacc[(e & 3) * NSEG + (e >> 2)], acc);
}

__global__ __launch_bounds__(512) void finalize_kernel(const double* __restrict__ gacc,
                                                       const float* __restrict__ tmean,
                                                       const float* __restrict__ tstd,
                                                       float* __restrict__ out) {
    int s = threadIdx.x;  // 512 threads, one per segment
    double cnt = gacc[s];
    double c = cnt > 1.0 ? cnt : 1.0;
    double mean_w = gacc[NSEG + s] / c;
    double mean_log = gacc[2 * NSEG + s] / c;
    double var = gacc[3 * NSEG + s] / c - mean_log * mean_log;
    if (var < 0.0) var = 0.0;
    double std_w = sqrt(var + 1e-6);
    double dm = mean_w - (double)tmean[s];
    double dsd = std_w - (double)tstd[s];
    double term = 0.5 * dm * dm + 0.5 * dsd * dsd;

#pragma unroll
    for (int off = 32; off > 0; off >>= 1) term += __shfl_down(term, off, 64);

    __shared__ double part[8];
    int wid = threadIdx.x >> 6;
    if ((threadIdx.x & 63) == 0) part[wid] = term;
    __syncthreads();
    if (threadIdx.x == 0) {
        double t = 0.0;
#pragma unroll
        for (int i = 0; i < 8; ++i) t += part[i];
        out[0] = (float)((t / (double)NSEG) * 0.01);
    }
}

extern "C" void kernel_launch(void* const* d_in, const int* in_sizes, int n_in,
                              void* d_out, int out_size, void* d_ws, size_t ws_size,
                              hipStream_t stream) {
    const float* x = (const float*)d_in[0];
    const int* idx = (const int*)d_in[1];
    const float* tmean = (const float*)d_in[2];
    const float* tstd = (const float*)d_in[3];
    float* out = (float*)d_out;

    double* gacc = (double*)d_ws;
    float* parts = (float*)((char*)d_ws + 4 * NSEG * sizeof(double));
    size_t need = 4 * NSEG * sizeof(double) + (size_t)MAIN_GRID * NSEG * 4 * sizeof(float);
    int use_parts = (ws_size >= need) ? 1 : 0;

    int n = in_sizes[0];
    int n4 = n / 4;  // N_EDGES = 16777216, divisible by 4

    zero_ws_kernel<<<2, 1024, 0, stream>>>(gacc);
    seg_stats_kernel<<<MAIN_GRID, MAIN_BLOCK, 0, stream>>>((const float4*)x, (const int4*)idx,
                                                           parts, gacc, n4, use_parts);
    if (use_parts)
        reduce_partials_kernel<<<8 * RP_CHUNKS, 256, 0, stream>>>(parts, gacc);
    finalize_kernel<<<1, 512, 0, stream>>>(gacc, tmean, tstd, out);
}